// Round 7
// baseline (287.882 us; speedup 1.0000x reference)
//
#include <hip/hip_runtime.h>
#include <stdint.h>
#include <type_traits>

#define M_DIM 16384
#define N_DIM 2048
#define K_DIM 2048

typedef __bf16 bf16_t;
typedef __bf16 bf16x8 __attribute__((ext_vector_type(8)));
typedef __bf16 bf16x4 __attribute__((ext_vector_type(4)));
typedef float f32x4 __attribute__((ext_vector_type(4)));

template <int N> using ic = std::integral_constant<int, N>;

#define SB0() __builtin_amdgcn_sched_barrier(0)

__device__ __forceinline__ void gload_lds16(const void* g, void* l) {
  __builtin_amdgcn_global_load_lds(
      (const __attribute__((address_space(1))) void*)g,
      (__attribute__((address_space(3))) void*)l, 16, 0, 0);
}

// float -> bf16 (RNE). SIGN applies sign() first (exact in bf16).
template <bool SIGN>
__global__ void cvt_kernel(const float* __restrict__ in, bf16_t* __restrict__ out) {
  long long i = ((long long)blockIdx.x * 256 + threadIdx.x) * 8;
  const float4* p = (const float4*)(in + i);
  float4 v0 = p[0];
  float4 v1 = p[1];
  float f[8] = {v0.x, v0.y, v0.z, v0.w, v1.x, v1.y, v1.z, v1.w};
  bf16x8 r;
#pragma unroll
  for (int j = 0; j < 8; ++j) {
    float v = f[j];
    if (SIGN) v = (v > 0.f) ? 1.f : ((v < 0.f) ? -1.f : 0.f);
    r[j] = (bf16_t)v;
  }
  *(bf16x8*)(out + i) = r;
}

// ============================================================================
// 256x256 tile, BK=64, 8 waves (2Mx4N, 128x64/wave), 2-buffer LDS (2x64KB).
// Round-7: ONE barrier per K-tile; all ds_reads issue under MFMA cover.
// Per tile t (slot TB = par(t)), with aLo(t) preloaded last tile:
//  Phase A: issue bL,bH,aH reads (16, slot TB, valid+collective since BAR of
//           t-1); MFMA Q1(aLo x bL), Q2(aLo x bH), Q3(aH x bH) — compiler
//           inserts counted lgkm per dep, reads stream under MFMA;
//           vmcnt(0) [drains tile-(t+1) staging issued during t-1, ~free];
//           BAR -> (a) slot t+1 collectively valid, (b) all waves' slot-t
//           reads retired (consumed by Q1-Q3 data-deps before BAR).
//  Phase B: stage tile t+2 into TB (WAR safe per (b)); preload aLo(t+1) from
//           other buffer (valid per (a)); MFMA Q4(aH x bL) reg-only as cover.
// No second barrier: fast wave's next-tile reads touch par(t+1) only; its
// next staging is gated by the next BAR. Max skew 1 tile.
// LDS swizzle: phys_col = col ^ ((row&7)<<4) on 128B rows (rounds 5/6:
// zero conflicts); linear gload_lds dest + inverse-swizzled global source.
// ============================================================================
__global__ __launch_bounds__(512, 2) void gemm1b(const bf16_t* __restrict__ A,
                                                 const bf16_t* __restrict__ B,
                                                 const float* __restrict__ alpha_p,
                                                 float* __restrict__ C) {
  extern __shared__ char smem[];  // buf(t&1): A @ tb+0 (32KB), B @ tb+32768

  const int tid = threadIdx.x;
  const int lane = tid & 63;
  const int wid = tid >> 6;
  const int wm = wid >> 2;   // 0..1 -> rows wm*128..+127
  const int wn = wid & 3;    // 0..3 -> cols wn*64..+63

  // XCD-aware bijective swizzle (512 blocks, 512 % 8 == 0)
  const int bid = blockIdx.x;
  const int swz = (bid & 7) * 64 + (bid >> 3);
  const int bm = swz >> 3;   // 0..63
  const int bn = swz & 7;    // 0..7

  const int q = lane >> 4;   // 16B col-slot within K
  const int r15 = lane & 15; // frag row

  // ---- Fragment LDS byte bases (add TB + mt*2048 / nt*2048 immediates) ----
  const int swc = (r15 & 7) << 4;
  int aoff[2], boff[2];
#pragma unroll
  for (int k = 0; k < 2; ++k) {
    int ck = (k * 64 + q * 16) ^ swc;
    aoff[k] = (wm * 128 + r15) * 128 + ck;
    boff[k] = 32768 + (wn * 64 + r15) * 128 + ck;
  }

  // ---- Stage pointers (tile 0): inverse-swizzled global src, linear dest ----
  const char* asrc[4];
  const char* bsrc[4];
  int adsto[4], bdsto[4];
#pragma unroll
  for (int j = 0; j < 4; ++j) {
    int P = j * 8192 + tid * 16;                 // phys byte in 32KB tile
    int row = P >> 7;                            // 0..255
    int lcol = (P & 127) ^ ((row & 7) << 4);     // logical K-byte in row
    asrc[j] = (const char*)A + (size_t)(bm * 256 + row) * (K_DIM * 2) + lcol;
    bsrc[j] = (const char*)B + (size_t)(bn * 256 + row) * (K_DIM * 2) + lcol;
    adsto[j] = j * 8192 + wid * 1024;            // wave-uniform linear dest
    bdsto[j] = 32768 + j * 8192 + wid * 1024;
  }

  f32x4 acc[8][4];
#pragma unroll
  for (int mt = 0; mt < 8; ++mt)
#pragma unroll
    for (int nt = 0; nt < 4; ++nt) acc[mt][nt] = (f32x4){0.f, 0.f, 0.f, 0.f};

  bf16x8 aLo[4][2];  // persistent: mt0-3 frags of current tile

  // ---- Prologue: stage tiles 0,1; wait tile 0; preload aLo(0) ----
#pragma unroll
  for (int t = 0; t < 2; ++t) {
#pragma unroll
    for (int j = 0; j < 4; ++j)
      gload_lds16(asrc[j] + t * 128, smem + t * 65536 + adsto[j]);
#pragma unroll
    for (int j = 0; j < 4; ++j)
      gload_lds16(bsrc[j] + t * 128, smem + t * 65536 + bdsto[j]);
  }
  asm volatile("s_waitcnt vmcnt(8)" ::: "memory");
  SB0();
  __builtin_amdgcn_s_barrier();
  SB0();
#pragma unroll
  for (int mt = 0; mt < 4; ++mt)
#pragma unroll
    for (int k = 0; k < 2; ++k)
      aLo[mt][k] = *(const bf16x8*)(smem + aoff[k] + mt * 2048);

  // One K-tile. U = t&1. MODE: 0 = steady (stage t+2, preload aLo(t+1));
  // 1 = t=30 (no stage, preload); 2 = t=31 (no stage, no preload).
  auto kstep = [&](auto UC, auto MC) {
    constexpr int U = UC.value;
    constexpr int MODE = MC.value;
    constexpr int TB = U * 65536;
    constexpr int NTB = ((U + 1) & 1) * 65536;
    constexpr int GOFF = (U + 2) * 128;

    bf16x8 bL[2][2], bH[2][2], aH[4][2];

    // ======== Phase A: issue 16 reads; MFMA Q1,Q2,Q3 (48) ========
#pragma unroll
    for (int nt = 0; nt < 2; ++nt)
#pragma unroll
      for (int k = 0; k < 2; ++k)
        bL[nt][k] = *(const bf16x8*)(smem + TB + boff[k] + nt * 2048);
#pragma unroll
    for (int nt = 0; nt < 2; ++nt)
#pragma unroll
      for (int k = 0; k < 2; ++k)
        bH[nt][k] = *(const bf16x8*)(smem + TB + boff[k] + (2 + nt) * 2048);
#pragma unroll
    for (int mt = 0; mt < 4; ++mt)
#pragma unroll
      for (int k = 0; k < 2; ++k)
        aH[mt][k] = *(const bf16x8*)(smem + TB + aoff[k] + (4 + mt) * 2048);
    SB0();
    __builtin_amdgcn_s_setprio(1);
    // Q1: aLo x bL
#pragma unroll
    for (int k = 0; k < 2; ++k)
#pragma unroll
      for (int mt = 0; mt < 4; ++mt)
#pragma unroll
        for (int nt = 0; nt < 2; ++nt)
          acc[mt][nt] = __builtin_amdgcn_mfma_f32_16x16x32_bf16(
              aLo[mt][k], bL[nt][k], acc[mt][nt], 0, 0, 0);
    // Q2: aLo x bH
#pragma unroll
    for (int k = 0; k < 2; ++k)
#pragma unroll
      for (int mt = 0; mt < 4; ++mt)
#pragma unroll
        for (int nt = 0; nt < 2; ++nt)
          acc[mt][2 + nt] = __builtin_amdgcn_mfma_f32_16x16x32_bf16(
              aLo[mt][k], bH[nt][k], acc[mt][2 + nt], 0, 0, 0);
    // Q3: aH x bH
#pragma unroll
    for (int k = 0; k < 2; ++k)
#pragma unroll
      for (int mt = 0; mt < 4; ++mt)
#pragma unroll
        for (int nt = 0; nt < 2; ++nt)
          acc[4 + mt][2 + nt] = __builtin_amdgcn_mfma_f32_16x16x32_bf16(
              aH[mt][k], bH[nt][k], acc[4 + mt][2 + nt], 0, 0, 0);
    __builtin_amdgcn_s_setprio(0);
    SB0();
    asm volatile("s_waitcnt vmcnt(0)" ::: "memory");  // drains >=1-tile-old loads
    SB0();
    __builtin_amdgcn_s_barrier();
    SB0();

    // ======== Phase B: stage t+2; preload aLo(t+1); MFMA Q4 (16) ========
    if constexpr (MODE == 0) {
#pragma unroll
      for (int j = 0; j < 4; ++j)
        gload_lds16(bsrc[j] + GOFF, smem + TB + bdsto[j]);
#pragma unroll
      for (int j = 0; j < 4; ++j)
        gload_lds16(asrc[j] + GOFF, smem + TB + adsto[j]);
    }
    if constexpr (MODE != 2) {
#pragma unroll
      for (int mt = 0; mt < 4; ++mt)
#pragma unroll
        for (int k = 0; k < 2; ++k)
          aLo[mt][k] = *(const bf16x8*)(smem + NTB + aoff[k] + mt * 2048);
    }
    SB0();
    __builtin_amdgcn_s_setprio(1);
    // Q4: aH x bL (reg-only; covers stage + preload issue)
#pragma unroll
    for (int k = 0; k < 2; ++k)
#pragma unroll
      for (int mt = 0; mt < 4; ++mt)
#pragma unroll
        for (int nt = 0; nt < 2; ++nt)
          acc[4 + mt][nt] = __builtin_amdgcn_mfma_f32_16x16x32_bf16(
              aH[mt][k], bL[nt][k], acc[4 + mt][nt], 0, 0, 0);
    __builtin_amdgcn_s_setprio(0);
    SB0();
  };

#pragma unroll 1
  for (int T = 0; T < 15; ++T) {
    kstep(ic<0>{}, ic<0>{});
    kstep(ic<1>{}, ic<0>{});
#pragma unroll
    for (int j = 0; j < 4; ++j) { asrc[j] += 256; bsrc[j] += 256; }
  }
  kstep(ic<0>{}, ic<1>{});   // t=30: no stage, preload aLo(31)
  kstep(ic<1>{}, ic<2>{});   // t=31: no stage, no preload

  // ---- Epilogue: 16x16 C/D layout col=lane&15, row=(lane>>4)*4+reg ----
  const float alpha = alpha_p[0];
  const int rbase = bm * 256 + wm * 128 + q * 4;
  const int cbase = bn * 256 + wn * 64 + r15;
#pragma unroll
  for (int mt = 0; mt < 8; ++mt)
#pragma unroll
    for (int nt = 0; nt < 4; ++nt)
#pragma unroll
      for (int r = 0; r < 4; ++r)
        C[(size_t)(rbase + mt * 16 + r) * N_DIM + cbase + nt * 16] =
            alpha * acc[mt][nt][r];
}

// ---- Workspace-free fallback (round-1 verified structure, f32 reg-staged) ----
__global__ __launch_bounds__(256) void gemm_fallback(const float* __restrict__ Ap,
                                                     const float* __restrict__ Bp,
                                                     const float* __restrict__ alpha_p,
                                                     float* __restrict__ C) {
  __shared__ bf16_t Asf[128 * 32];
  __shared__ bf16_t Bsf[128 * 32];
  const int tid = threadIdx.x;
  const int lane = tid & 63;
  const int wid = tid >> 6;
  const int wr = wid >> 1;
  const int wc = wid & 1;
  const int cpx = gridDim.x >> 3;
  const int bid = blockIdx.x;
  const int swz = (bid & 7) * cpx + (bid >> 3);
  const int NB = N_DIM / 128;
  const int bm = swz / NB;
  const int bn = swz % NB;
  f32x4 acc[4][4];
#pragma unroll
  for (int m = 0; m < 4; ++m)
#pragma unroll
    for (int n = 0; n < 4; ++n) acc[m][n] = (f32x4){0.f, 0.f, 0.f, 0.f};
  const int r0 = lane & 15;
  const int ko = (lane >> 4) * 8;
  for (int kk = 0; kk < K_DIM; kk += 32) {
    const float* Af = Ap + (size_t)bm * 128 * K_DIM + kk;
    const float* Bf = Bp + (size_t)bn * 128 * K_DIM + kk;
#pragma unroll
    for (int qq = 0; qq < 4; ++qq) {
      int e = qq * 256 + tid;
      int row = e >> 3;
      int kc = (e & 7) << 2;
      float4 v = *(const float4*)(Af + (size_t)row * K_DIM + kc);
      bf16x4 tv;
      tv[0] = (bf16_t)v.x; tv[1] = (bf16_t)v.y; tv[2] = (bf16_t)v.z; tv[3] = (bf16_t)v.w;
      *(bf16x4*)&Asf[e * 4] = tv;
    }
#pragma unroll
    for (int qq = 0; qq < 4; ++qq) {
      int e = qq * 256 + tid;
      int row = e >> 3;
      int kc = (e & 7) << 2;
      float4 v = *(const float4*)(Bf + (size_t)row * K_DIM + kc);
      float s[4] = {v.x, v.y, v.z, v.w};
      bf16x4 tv;
#pragma unroll
      for (int j = 0; j < 4; ++j)
        tv[j] = (bf16_t)((s[j] > 0.f) ? 1.f : ((s[j] < 0.f) ? -1.f : 0.f));
      *(bf16x4*)&Bsf[e * 4] = tv;
    }
    __syncthreads();
    bf16x8 a[4], b[4];
#pragma unroll
    for (int m = 0; m < 4; ++m) a[m] = *(const bf16x8*)&Asf[(wr * 64 + m * 16 + r0) * 32 + ko];
#pragma unroll
    for (int n = 0; n < 4; ++n) b[n] = *(const bf16x8*)&Bsf[(wc * 64 + n * 16 + r0) * 32 + ko];
#pragma unroll
    for (int m = 0; m < 4; ++m)
#pragma unroll
      for (int n = 0; n < 4; ++n)
        acc[m][n] = __builtin_amdgcn_mfma_f32_16x16x32_bf16(a[m], b[n], acc[m][n], 0, 0, 0);
    __syncthreads();
  }
  const float alpha = alpha_p[0];
  const int rowb = bm * 128 + wr * 64 + (lane >> 4) * 4;
  const int colb = bn * 128 + wc * 64 + r0;
#pragma unroll
  for (int m = 0; m < 4; ++m)
#pragma unroll
    for (int n = 0; n < 4; ++n)
#pragma unroll
      for (int r = 0; r < 4; ++r)
        C[(size_t)(rowb + m * 16 + r) * N_DIM + colb + n * 16] = alpha * acc[m][n][r];
}

extern "C" void kernel_launch(void* const* d_in, const int* in_sizes, int n_in,
                              void* d_out, int out_size, void* d_ws, size_t ws_size,
                              hipStream_t stream) {
  const float* x = (const float*)d_in[0];
  const float* w = (const float*)d_in[1];
  const float* alpha = (const float*)d_in[2];
  float* out = (float*)d_out;

  const size_t nx = (size_t)M_DIM * K_DIM;
  const size_t nw = (size_t)N_DIM * K_DIM;
  const size_t need = (nx + nw) * sizeof(bf16_t);

  if (ws_size >= need) {
    bf16_t* xb = (bf16_t*)d_ws;
    bf16_t* wb = xb + nx;
    cvt_kernel<false><<<(int)(nx / 2048), 256, 0, stream>>>(x, xb);
    cvt_kernel<true><<<(int)(nw / 2048), 256, 0, stream>>>(w, wb);
    (void)hipFuncSetAttribute((const void*)gemm1b,
                              hipFuncAttributeMaxDynamicSharedMemorySize, 131072);
    gemm1b<<<512, 512, 131072, stream>>>(xb, wb, alpha, out);
  } else {
    gemm_fallback<<<(M_DIM / 128) * (N_DIM / 128), 256, 0, stream>>>(x, w, alpha, out);
  }
}

// Round 8
// 215.924 us; speedup vs baseline: 1.3333x; 1.3333x over previous
//
#include <hip/hip_runtime.h>
#include <stdint.h>
#include <type_traits>

#define M_DIM 16384
#define N_DIM 2048
#define K_DIM 2048

typedef __bf16 bf16_t;
typedef __bf16 bf16x8 __attribute__((ext_vector_type(8)));
typedef __bf16 bf16x4 __attribute__((ext_vector_type(4)));
typedef float f32x4 __attribute__((ext_vector_type(4)));

template <int N> using ic = std::integral_constant<int, N>;

#define SB0() __builtin_amdgcn_sched_barrier(0)

__device__ __forceinline__ void gload_lds16(const void* g, void* l) {
  __builtin_amdgcn_global_load_lds(
      (const __attribute__((address_space(1))) void*)g,
      (__attribute__((address_space(3))) void*)l, 16, 0, 0);
}

// float -> bf16 (RNE). SIGN applies sign() first (exact in bf16).
template <bool SIGN>
__global__ void cvt_kernel(const float* __restrict__ in, bf16_t* __restrict__ out) {
  long long i = ((long long)blockIdx.x * 256 + threadIdx.x) * 8;
  const float4* p = (const float4*)(in + i);
  float4 v0 = p[0];
  float4 v1 = p[1];
  float f[8] = {v0.x, v0.y, v0.z, v0.w, v1.x, v1.y, v1.z, v1.w};
  bf16x8 r;
#pragma unroll
  for (int j = 0; j < 8; ++j) {
    float v = f[j];
    if (SIGN) v = (v > 0.f) ? 1.f : ((v < 0.f) ? -1.f : 0.f);
    r[j] = (bf16_t)v;
  }
  *(bf16x8*)(out + i) = r;
}

// ============================================================================
// 256x256 tile, BK=64, 8 waves (2Mx4N, 128x64/wave), 2-buffer LDS (2x64KB).
// Round-5 verified skeleton: 4 phases/tile, 2 barriers/phase, stage B@P3 /
// A@P4 into current slot (after its readers retired), vmcnt(8) at P4 (never
// 0 in main loop), swizzle phys_col = col ^ ((row&7)<<4), linear gload_lds
// dest + inverse-swizzled global source.
// Round-8 change ONLY: ds_reads issue ONE PHASE EARLY with compiler-counted
// lgkm waits (no lgkmcnt(0) serialization):
//   P1: issue bH(t)[4];            Q1 aLo x bL   (auto lgkm(4): G0 done)
//   P2: issue aH(t)[8];            Q2 aLo x bH   (auto lgkm(8): bH done)
//   P3: stage B(t+2);              Q3 aH x bH    (auto lgkm(0): aH done)
//   P4: stage A(t+2); vmcnt(8); BAR; issue G0(t+1)={aLo,bL}[12] (slot t+1
//       collectively valid after this barrier); Q4 aH x bL (reg-only cover)
// WAR: bH retired @P2-lgkm < stage-B @P3-top (barrier-separated); aH retired
// @P3-lgkm < stage-A @P4-top. RAW: G0(t+1) issued only after vmcnt(8)+BAR.
// ============================================================================
__global__ __launch_bounds__(512, 2) void gemm4s(const bf16_t* __restrict__ A,
                                                 const bf16_t* __restrict__ B,
                                                 const float* __restrict__ alpha_p,
                                                 float* __restrict__ C) {
  extern __shared__ char smem[];  // buf(t&1): A @ tb+0 (32KB), B @ tb+32768

  const int tid = threadIdx.x;
  const int lane = tid & 63;
  const int wid = tid >> 6;
  const int wm = wid >> 2;   // 0..1 -> rows wm*128..+127
  const int wn = wid & 3;    // 0..3 -> cols wn*64..+63

  // XCD-aware bijective swizzle (512 blocks, 512 % 8 == 0)
  const int bid = blockIdx.x;
  const int swz = (bid & 7) * 64 + (bid >> 3);
  const int bm = swz >> 3;   // 0..63
  const int bn = swz & 7;    // 0..7

  const int q = lane >> 4;   // 16B col-slot within K
  const int r15 = lane & 15; // frag row

  // ---- Fragment LDS byte bases (add TB + mt*2048 / nt*2048 immediates) ----
  const int swc = (r15 & 7) << 4;
  int aoff[2], boff[2];
#pragma unroll
  for (int k = 0; k < 2; ++k) {
    int ck = (k * 64 + q * 16) ^ swc;
    aoff[k] = (wm * 128 + r15) * 128 + ck;
    boff[k] = 32768 + (wn * 64 + r15) * 128 + ck;
  }

  // ---- Stage pointers (tile 0): inverse-swizzled global src, linear dest.
  //      asrc[j] = asrc0 + j*64 rows (j*262144 bytes); dest = j*8192+wid*1024.
  const char* asrc0;
  const char* bsrc0;
  {
    int P = tid * 16;
    int row = P >> 7;
    int lcol = (P & 127) ^ ((row & 7) << 4);
    asrc0 = (const char*)A + (size_t)(bm * 256 + row) * (K_DIM * 2) + lcol;
    bsrc0 = (const char*)B + (size_t)(bn * 256 + row) * (K_DIM * 2) + lcol;
  }
  const int dsto = wid * 1024;

  f32x4 acc[8][4];
#pragma unroll
  for (int mt = 0; mt < 8; ++mt)
#pragma unroll
    for (int nt = 0; nt < 4; ++nt) acc[mt][nt] = (f32x4){0.f, 0.f, 0.f, 0.f};

  // Persistent fragments (constexpr-indexed only)
  bf16x8 aLo[4][2], aH[4][2], bH[2][2], bL[2][2][2];  // bL[parity][nt][k]

  // ---- Prologue: stage tiles 0,1; wait tile 0; issue G0(0) ----
#pragma unroll
  for (int t = 0; t < 2; ++t) {
#pragma unroll
    for (int j = 0; j < 4; ++j)
      gload_lds16(asrc0 + (size_t)j * 262144 + t * 128,
                  smem + t * 65536 + j * 8192 + dsto);
#pragma unroll
    for (int j = 0; j < 4; ++j)
      gload_lds16(bsrc0 + (size_t)j * 262144 + t * 128,
                  smem + t * 65536 + 32768 + j * 8192 + dsto);
  }
  asm volatile("s_waitcnt vmcnt(8)" ::: "memory");
  SB0();
  __builtin_amdgcn_s_barrier();
  SB0();
#pragma unroll
  for (int mt = 0; mt < 4; ++mt)
#pragma unroll
    for (int k = 0; k < 2; ++k)
      aLo[mt][k] = *(const bf16x8*)(smem + aoff[k] + mt * 2048);
#pragma unroll
  for (int nt = 0; nt < 2; ++nt)
#pragma unroll
    for (int k = 0; k < 2; ++k)
      bL[0][nt][k] = *(const bf16x8*)(smem + boff[k] + nt * 2048);
  SB0();

  // One K-tile. U = t&1. MODE: 0 steady; 1 = t=30 (no stage, vmcnt(0),
  // preload G0(31)); 2 = t=31 (no stage, no vmcnt, no preload).
  auto kstep = [&](auto UC, auto MC) {
    constexpr int U = UC.value;
    constexpr int MODE = MC.value;
    constexpr int TB = U * 65536;
    constexpr int NTB = ((U + 1) & 1) * 65536;
    constexpr int GOFF = (U + 2) * 128;
    constexpr int PAR = U & 1;

    // ---- P1: issue bH(t); Q1 = aLo x bL (auto counted lgkm) ----
#pragma unroll
    for (int nt = 0; nt < 2; ++nt)
#pragma unroll
      for (int k = 0; k < 2; ++k)
        bH[nt][k] = *(const bf16x8*)(smem + TB + boff[k] + (2 + nt) * 2048);
    SB0();
    __builtin_amdgcn_s_barrier();
    __builtin_amdgcn_s_setprio(1);
#pragma unroll
    for (int k = 0; k < 2; ++k)
#pragma unroll
      for (int mt = 0; mt < 4; ++mt)
#pragma unroll
        for (int nt = 0; nt < 2; ++nt)
          acc[mt][nt] = __builtin_amdgcn_mfma_f32_16x16x32_bf16(
              aLo[mt][k], bL[PAR][nt][k], acc[mt][nt], 0, 0, 0);
    __builtin_amdgcn_s_setprio(0);
    SB0();
    __builtin_amdgcn_s_barrier();

    // ---- P2: issue aH(t); Q2 = aLo x bH ----
#pragma unroll
    for (int mt = 0; mt < 4; ++mt)
#pragma unroll
      for (int k = 0; k < 2; ++k)
        aH[mt][k] = *(const bf16x8*)(smem + TB + aoff[k] + (4 + mt) * 2048);
    SB0();
    __builtin_amdgcn_s_barrier();
    __builtin_amdgcn_s_setprio(1);
#pragma unroll
    for (int k = 0; k < 2; ++k)
#pragma unroll
      for (int mt = 0; mt < 4; ++mt)
#pragma unroll
        for (int nt = 0; nt < 2; ++nt)
          acc[mt][2 + nt] = __builtin_amdgcn_mfma_f32_16x16x32_bf16(
              aLo[mt][k], bH[nt][k], acc[mt][2 + nt], 0, 0, 0);
    __builtin_amdgcn_s_setprio(0);
    SB0();
    __builtin_amdgcn_s_barrier();

    // ---- P3: stage B(t+2); Q3 = aH x bH ----
    if constexpr (MODE == 0) {
#pragma unroll
      for (int j = 0; j < 4; ++j)
        gload_lds16(bsrc0 + (size_t)j * 262144 + GOFF,
                    smem + TB + 32768 + j * 8192 + dsto);
    }
    SB0();
    __builtin_amdgcn_s_barrier();
    __builtin_amdgcn_s_setprio(1);
#pragma unroll
    for (int k = 0; k < 2; ++k)
#pragma unroll
      for (int mt = 0; mt < 4; ++mt)
#pragma unroll
        for (int nt = 0; nt < 2; ++nt)
          acc[4 + mt][2 + nt] = __builtin_amdgcn_mfma_f32_16x16x32_bf16(
              aH[mt][k], bH[nt][k], acc[4 + mt][2 + nt], 0, 0, 0);
    __builtin_amdgcn_s_setprio(0);
    SB0();
    __builtin_amdgcn_s_barrier();

    // ---- P4: stage A(t+2); vmcnt; BAR; issue G0(t+1); Q4 = aH x bL ----
    if constexpr (MODE == 0) {
#pragma unroll
      for (int j = 0; j < 4; ++j)
        gload_lds16(asrc0 + (size_t)j * 262144 + GOFF,
                    smem + TB + j * 8192 + dsto);
      asm volatile("s_waitcnt vmcnt(8)" ::: "memory");  // tile t+1 landed
    } else if constexpr (MODE == 1) {
      asm volatile("s_waitcnt vmcnt(0)" ::: "memory");  // tile 31 landed
    }
    SB0();
    __builtin_amdgcn_s_barrier();   // slot t+1 collectively valid
    SB0();
    if constexpr (MODE != 2) {
#pragma unroll
      for (int mt = 0; mt < 4; ++mt)
#pragma unroll
        for (int k = 0; k < 2; ++k)
          aLo[mt][k] = *(const bf16x8*)(smem + NTB + aoff[k] + mt * 2048);
#pragma unroll
      for (int nt = 0; nt < 2; ++nt)
#pragma unroll
        for (int k = 0; k < 2; ++k)
          bL[PAR ^ 1][nt][k] = *(const bf16x8*)(smem + NTB + boff[k] + nt * 2048);
    }
    SB0();
    __builtin_amdgcn_s_setprio(1);
#pragma unroll
    for (int k = 0; k < 2; ++k)
#pragma unroll
      for (int mt = 0; mt < 4; ++mt)
#pragma unroll
        for (int nt = 0; nt < 2; ++nt)
          acc[4 + mt][nt] = __builtin_amdgcn_mfma_f32_16x16x32_bf16(
              aH[mt][k], bL[PAR][nt][k], acc[4 + mt][nt], 0, 0, 0);
    __builtin_amdgcn_s_setprio(0);
    SB0();
    __builtin_amdgcn_s_barrier();
  };

#pragma unroll 1
  for (int T = 0; T < 15; ++T) {
    kstep(ic<0>{}, ic<0>{});
    kstep(ic<1>{}, ic<0>{});
    asrc0 += 256;
    bsrc0 += 256;
  }
  kstep(ic<0>{}, ic<1>{});   // t=30: no stage, vmcnt(0), preload G0(31)
  kstep(ic<1>{}, ic<2>{});   // t=31: no stage, no vmcnt, no preload

  // ---- Epilogue: 16x16 C/D layout col=lane&15, row=(lane>>4)*4+reg ----
  const float alpha = alpha_p[0];
  const int rbase = bm * 256 + wm * 128 + q * 4;
  const int cbase = bn * 256 + wn * 64 + r15;
#pragma unroll
  for (int mt = 0; mt < 8; ++mt)
#pragma unroll
    for (int nt = 0; nt < 4; ++nt)
#pragma unroll
      for (int r = 0; r < 4; ++r)
        C[(size_t)(rbase + mt * 16 + r) * N_DIM + cbase + nt * 16] =
            alpha * acc[mt][nt][r];
}

// ---- Workspace-free fallback (round-1 verified structure, f32 reg-staged) ----
__global__ __launch_bounds__(256) void gemm_fallback(const float* __restrict__ Ap,
                                                     const float* __restrict__ Bp,
                                                     const float* __restrict__ alpha_p,
                                                     float* __restrict__ C) {
  __shared__ bf16_t Asf[128 * 32];
  __shared__ bf16_t Bsf[128 * 32];
  const int tid = threadIdx.x;
  const int lane = tid & 63;
  const int wid = tid >> 6;
  const int wr = wid >> 1;
  const int wc = wid & 1;
  const int cpx = gridDim.x >> 3;
  const int bid = blockIdx.x;
  const int swz = (bid & 7) * cpx + (bid >> 3);
  const int NB = N_DIM / 128;
  const int bm = swz / NB;
  const int bn = swz % NB;
  f32x4 acc[4][4];
#pragma unroll
  for (int m = 0; m < 4; ++m)
#pragma unroll
    for (int n = 0; n < 4; ++n) acc[m][n] = (f32x4){0.f, 0.f, 0.f, 0.f};
  const int r0 = lane & 15;
  const int ko = (lane >> 4) * 8;
  for (int kk = 0; kk < K_DIM; kk += 32) {
    const float* Af = Ap + (size_t)bm * 128 * K_DIM + kk;
    const float* Bf = Bp + (size_t)bn * 128 * K_DIM + kk;
#pragma unroll
    for (int qq = 0; qq < 4; ++qq) {
      int e = qq * 256 + tid;
      int row = e >> 3;
      int kc = (e & 7) << 2;
      float4 v = *(const float4*)(Af + (size_t)row * K_DIM + kc);
      bf16x4 tv;
      tv[0] = (bf16_t)v.x; tv[1] = (bf16_t)v.y; tv[2] = (bf16_t)v.z; tv[3] = (bf16_t)v.w;
      *(bf16x4*)&Asf[e * 4] = tv;
    }
#pragma unroll
    for (int qq = 0; qq < 4; ++qq) {
      int e = qq * 256 + tid;
      int row = e >> 3;
      int kc = (e & 7) << 2;
      float4 v = *(const float4*)(Bf + (size_t)row * K_DIM + kc);
      float s[4] = {v.x, v.y, v.z, v.w};
      bf16x4 tv;
#pragma unroll
      for (int j = 0; j < 4; ++j)
        tv[j] = (bf16_t)((s[j] > 0.f) ? 1.f : ((s[j] < 0.f) ? -1.f : 0.f));
      *(bf16x4*)&Bsf[e * 4] = tv;
    }
    __syncthreads();
    bf16x8 a[4], b[4];
#pragma unroll
    for (int m = 0; m < 4; ++m) a[m] = *(const bf16x8*)&Asf[(wr * 64 + m * 16 + r0) * 32 + ko];
#pragma unroll
    for (int n = 0; n < 4; ++n) b[n] = *(const bf16x8*)&Bsf[(wc * 64 + n * 16 + r0) * 32 + ko];
#pragma unroll
    for (int m = 0; m < 4; ++m)
#pragma unroll
      for (int n = 0; n < 4; ++n)
        acc[m][n] = __builtin_amdgcn_mfma_f32_16x16x32_bf16(a[m], b[n], acc[m][n], 0, 0, 0);
    __syncthreads();
  }
  const float alpha = alpha_p[0];
  const int rowb = bm * 128 + wr * 64 + (lane >> 4) * 4;
  const int colb = bn * 128 + wc * 64 + r0;
#pragma unroll
  for (int m = 0; m < 4; ++m)
#pragma unroll
    for (int n = 0; n < 4; ++n)
#pragma unroll
      for (int r = 0; r < 4; ++r)
        C[(size_t)(rowb + m * 16 + r) * N_DIM + colb + n * 16] = alpha * acc[m][n][r];
}

extern "C" void kernel_launch(void* const* d_in, const int* in_sizes, int n_in,
                              void* d_out, int out_size, void* d_ws, size_t ws_size,
                              hipStream_t stream) {
  const float* x = (const float*)d_in[0];
  const float* w = (const float*)d_in[1];
  const float* alpha = (const float*)d_in[2];
  float* out = (float*)d_out;

  const size_t nx = (size_t)M_DIM * K_DIM;
  const size_t nw = (size_t)N_DIM * K_DIM;
  const size_t need = (nx + nw) * sizeof(bf16_t);

  if (ws_size >= need) {
    bf16_t* xb = (bf16_t*)d_ws;
    bf16_t* wb = xb + nx;
    cvt_kernel<false><<<(int)(nx / 2048), 256, 0, stream>>>(x, xb);
    cvt_kernel<true><<<(int)(nw / 2048), 256, 0, stream>>>(w, wb);
    (void)hipFuncSetAttribute((const void*)gemm4s,
                              hipFuncAttributeMaxDynamicSharedMemorySize, 131072);
    gemm4s<<<512, 512, 131072, stream>>>(xb, wb, alpha, out);
  } else {
    gemm_fallback<<<(M_DIM / 128) * (N_DIM / 128), 256, 0, stream>>>(x, w, alpha, out);
  }
}